// Round 9
// baseline (1624.557 us; speedup 1.0000x reference)
//
#include <hip/hip_runtime.h>
#include <cstdint>
#include <cstddef>

typedef unsigned short u16;
typedef unsigned char u8;
typedef unsigned int u32;

typedef short s16x8 __attribute__((ext_vector_type(8)));
typedef float f32x4 __attribute__((ext_vector_type(4)));

#define MF(a,b,c) __builtin_amdgcn_mfma_f32_16x16x32_bf16((a),(b),(c),0,0,0)

// ---------------- helpers ----------------
__device__ __forceinline__ float b2f(u16 h){ u32 u = ((u32)h)<<16; float f; __builtin_memcpy(&f,&u,4); return f; }
__device__ __forceinline__ u16 f2b(float x){ u32 u; __builtin_memcpy(&u,&x,4); u += 0x7fffu + ((u>>16)&1u); return (u16)(u>>16); }
__device__ __forceinline__ float sigf(float x){ return __builtin_amdgcn_rcpf(1.f+__expf(-x)); }
__device__ __forceinline__ float tanh2(float x){
  float ax=fabsf(x); float e=__expf(-2.f*ax);
  float r=(1.f-e)*__builtin_amdgcn_rcpf(1.f+e);
  return x<0.f? -r : r;
}

// coherent write-through store (no stale copies anywhere; visible at coherence point)
__device__ __forceinline__ void st_u16_coh(u16* p, u16 v){
  asm volatile("global_store_short %0, %1, off sc0 sc1" :: "v"(p), "v"((u32)v) : "memory");
}
// pinned 16B load (weights -> registers, non-rematerializable)
__device__ __forceinline__ s16x8 gload16(const u16* p){
  s16x8 r;
  asm volatile("global_load_dwordx4 %0, %1, off" : "=v"(r) : "v"(p) : "memory");
  return r;
}
// coherent 16B load: reads at coherence point (never stale)
__device__ __forceinline__ s16x8 gload16_coh(const u16* p){
  s16x8 r;
  asm volatile("global_load_dwordx4 %0, %1, off sc0 sc1" : "=v"(r) : "v"(p) : "memory");
  return r;
}

// ---------------- mask dtype detection + packed mask codes ----------------
__global__ void detect_mask_mode(const u8* raw, int n, int* flag){
  __shared__ int cnt;
  int tid = threadIdx.x;
  if(tid==0) cnt=0;
  __syncthreads();
  int c=0;
  for(int i=tid;i<n;i+=blockDim.x) c += (raw[i]!=0);
  atomicAdd(&cnt, c);
  __syncthreads();
  if(tid==0) *flag = (cnt > (n>>2)) ? 1 : 0;  // 1 => byte-per-element layout
}

// code[i] = done | main<<1 | mainNext<<2
__global__ void build_mcode(const void* done_raw, const void* main_raw, u8* code, int n, const int* flag){
  int mode = *flag;
  for(int i = blockIdx.x*blockDim.x + threadIdx.x; i<n; i += gridDim.x*blockDim.x){
    u8 d, m, m2;
    if(mode){
      d = ((const u8*)done_raw)[i]!=0; m = ((const u8*)main_raw)[i]!=0;
      m2 = (i+256<n) ? (((const u8*)main_raw)[i+256]!=0) : (u8)0;
    } else {
      d = ((const int*)done_raw)[i]!=0; m = ((const int*)main_raw)[i]!=0;
      m2 = (i+256<n) ? (((const int*)main_raw)[i+256]!=0) : (u8)0;
    }
    code[i] = d | (m<<1) | (m2<<2);
  }
}

__global__ void zero_flags(int* p, int n){
  int i = threadIdx.x;
  if(i<n) p[i]=0;
}

// ---------------- conversions ----------------
__global__ void cvt_f32_bf16(const float* __restrict__ in, u16* __restrict__ out, int n4){
  int i = blockIdx.x*blockDim.x + threadIdx.x;
  if(i < n4){
    float4 v = ((const float4*)in)[i];
    ushort4 o;
    o.x=f2b(v.x); o.y=f2b(v.y); o.z=f2b(v.z); o.w=f2b(v.w);
    ((ushort4*)out)[i]=o;
  }
}

// in [R][C] f32  ->  out [C][R] bf16
__global__ void transpose_to_bf16(const float* __restrict__ in, u16* __restrict__ out, int R, int C){
  __shared__ float tile[64][65];
  int c0 = blockIdx.x*64, r0 = blockIdx.y*64;
  int tx = threadIdx.x & 63, ty = threadIdx.x >> 6;   // 256 threads
  for(int i=ty;i<64;i+=4) tile[i][tx] = in[(size_t)(r0+i)*C + c0 + tx];
  __syncthreads();
  for(int i=ty;i<64;i+=4) out[(size_t)(c0+i)*R + r0 + tx] = f2b(tile[tx][i]);
}

__global__ void init_hsel(const float* __restrict__ h1in, const float* __restrict__ h2in,
                          const u8* __restrict__ mcode, u16* __restrict__ hsel0){
  int i = blockIdx.x*blockDim.x + threadIdx.x;
  if(i < 256*1024){
    int row = i >> 10;
    hsel0[i] = f2b((mcode[row]&2) ? h1in[i] : h2in[i]);
  }
}

// ---------------- fused persistent kernel: x-GEMM + recurrence ----------------
// 256 blocks x 512 threads (8 waves), 1 block/CU. rg=bid>>5 (32-row chain),
// jg=bid&31 (32 hcols; bid%8 = jg%8 -> each XCD's Wi slice is 4 jg = 1MB, L2-hot).
// Wave: gate=wid>>1, kg=wid&1 (K-half). Wh^T frags reg-resident (asm-pinned,
// 128 VGPR/wave); Wi^T frags streamed per step with PLAIN loads (L2 hits,
// compiler-scheduled waits). ONE 64KB LDS buffer, time-multiplexed:
//   h-tile (critical) -> zpart alias (epilogue) -> x-tile (free zone),
// every transition barrier-separated. Sync skeleton = R6 exactly (proven):
// sc0sc1 write-through h + vmcnt(0) + barrier + relaxed flag; sc0sc1 point
// reads for h staging; no cache maintenance anywhere.
__global__ __launch_bounds__(512) __attribute__((amdgpu_waves_per_eu(2,2)))
void lstm_fused(
    const u16* __restrict__ xb, const u16* __restrict__ WiT,
    const u16* __restrict__ Wht, const float* __restrict__ bias,
    u16* __restrict__ hs0, u16* __restrict__ hs1,
    const float* __restrict__ c1i, const float* __restrict__ h1i,
    const float* __restrict__ c2i, const float* __restrict__ h2i,
    const u8* __restrict__ mcode, float* __restrict__ out,
    int* __restrict__ ready)
{
  __shared__ u16 As[32768];        // 64 KB, time-multiplexed (h / zpart / x)
  float* zpart = (float*)As;

  const int bid = blockIdx.x;
  const int rg = bid >> 5, jg = bid & 31;
  const int r0 = rg << 5, j0 = jg << 5;
  const int tid = threadIdx.x, wid = tid >> 6, lane = tid & 63;
  const int l15 = lane & 15, hi = lane >> 4;
  const int gate = wid >> 1, kg = wid & 1;
  const int srow = tid >> 4, sc16 = tid & 15;   // staging persona
  const int erow = tid >> 5, ecol = tid & 31;   // epilogue persona

  // ---- Wh^T fragments (once): 32 x s16x8 = 128 VGPRs, asm-pinned ----
  s16x8 breg[2][16];
  {
    #pragma unroll
    for(int n=0;n<2;n++){
      const u16* wp = Wht + ((size_t)(gate*1024 + j0 + n*16 + l15))*1024 + kg*512 + hi*8;
      #pragma unroll
      for(int kk=0;kk<16;kk++) breg[n][kk] = gload16(wp + kk*32);
    }
    asm volatile("s_waitcnt vmcnt(0)" ::: "memory");
    __builtin_amdgcn_sched_barrier(0);
  }

  // ---- Wi^T streaming pointers (t-invariant -> L2-hit every step) ----
  const u16* wip0 = WiT + ((size_t)(gate*1024 + j0      + l15))*1024 + kg*512 + hi*8;
  const u16* wip1 = WiT + ((size_t)(gate*1024 + j0 + 16 + l15))*1024 + kg*512 + hi*8;
  const float bias0 = kg ? 0.f : bias[gate*1024 + j0      + l15];
  const float bias1 = kg ? 0.f : bias[gate*1024 + j0 + 16 + l15];

  // ---- states into registers (once) ----
  float c1r[2],c2r[2],h1r[2],h2r[2];
  #pragma unroll
  for(int e=0;e<2;e++){
    size_t sidx = (size_t)(r0 + e*16 + erow)*1024 + j0 + ecol;
    c1r[e]=c1i[sidx]; c2r[e]=c2i[sidx]; h1r[e]=h1i[sidx]; h2r[e]=h2i[sidx];
  }

  // ---- LDS pointers (t-invariant; x and h share layout/swizzle) ----
  u16* pSh = &As[sc16*256 + ((srow ^ (sc16&7))<<3)];
  const u16* pAe = &As[kg*16384 + hi*256 + ((l15 ^  hi   )<<3)];
  const u16* pAo = &As[kg*16384 + hi*256 + ((l15 ^ (4+hi))<<3)];
  float* pzw = &zpart[((gate*2+kg)*32 + hi*4)*33 + l15];
  const float* pzr = &zpart[erow*33 + ecol];

  int* flag = ready + rg*32;

  f32x4 acc00, acc01, acc10, acc11;   // carry x@Wi+b into the next critical zone

  // ---- x phase (free zone): stage x rows into As, acc = x@Wi + b ----
  auto xphase = [&](const u16* xrow){
    s16x8 x0 = *(const s16x8*)(xrow + (0*16+sc16)*8);
    s16x8 x1 = *(const s16x8*)(xrow + (1*16+sc16)*8);
    s16x8 x2 = *(const s16x8*)(xrow + (2*16+sc16)*8);
    s16x8 x3 = *(const s16x8*)(xrow + (3*16+sc16)*8);
    s16x8 x4 = *(const s16x8*)(xrow + (4*16+sc16)*8);
    s16x8 x5 = *(const s16x8*)(xrow + (5*16+sc16)*8);
    s16x8 x6 = *(const s16x8*)(xrow + (6*16+sc16)*8);
    s16x8 x7 = *(const s16x8*)(xrow + (7*16+sc16)*8);
    *(s16x8*)(pSh + 0*4096) = x0;  *(s16x8*)(pSh + 1*4096) = x1;
    *(s16x8*)(pSh + 2*4096) = x2;  *(s16x8*)(pSh + 3*4096) = x3;
    *(s16x8*)(pSh + 4*4096) = x4;  *(s16x8*)(pSh + 5*4096) = x5;
    *(s16x8*)(pSh + 6*4096) = x6;  *(s16x8*)(pSh + 7*4096) = x7;
    __syncthreads();
    acc00 = (f32x4){bias0,bias0,bias0,bias0};
    acc01 = (f32x4){bias1,bias1,bias1,bias1};
    acc10 = acc00; acc11 = acc01;
    // 4 groups x 4 kk; plain loads (compiler-scheduled waits, correctness-safe)
    #pragma unroll
    for(int g=0;g<4;g++){
      s16x8 w0[4], w1[4];
      #pragma unroll
      for(int j=0;j<4;j++){
        w0[j] = *(const s16x8*)(wip0 + (g*4+j)*32);
        w1[j] = *(const s16x8*)(wip1 + (g*4+j)*32);
      }
      #pragma unroll
      for(int j=0;j<4;j++){
        int kk = g*4+j;
        const u16* p = (kk&1) ? pAo : pAe;
        s16x8 a0 = *(const s16x8*)(p + kk*1024);
        s16x8 a1 = *(const s16x8*)(p + kk*1024 + 128);
        acc00 = MF(a0, w0[j], acc00);
        acc01 = MF(a0, w1[j], acc01);
        acc10 = MF(a1, w0[j], acc10);
        acc11 = MF(a1, w1[j], acc11);
      }
    }
  };

  // ---- prologue: x-part for step 0 ----
  xphase(xb + (size_t)(r0+srow)*1024);

  for(int t=0;t<128;t++){
    u8 cd0 = mcode[t*256 + r0 + erow];
    u8 cd1 = mcode[t*256 + r0 + 16 + erow];

    // ---- chain wait (single spinner; others park at the barrier) ----
    if(t>0 && tid==0){
      while(__hip_atomic_load(flag, __ATOMIC_RELAXED, __HIP_MEMORY_SCOPE_AGENT) < 32*t)
        __builtin_amdgcn_s_sleep(1);
    }
    __syncthreads();                       // also: all x-MFMA As reads retired
    __builtin_amdgcn_sched_barrier(0);

    const u16* hinp = (t&1) ? hs1 : hs0;
    u16* houtp = (t&1) ? hs0 : hs1;

    // ---- stage h(t-1): coherent point-reads -> swizzled LDS (R6 exact) ----
    {
      const u16* hrow = hinp + (size_t)(r0+srow)*1024;
      s16x8 h0 = gload16_coh(hrow + (0*16+sc16)*8);
      s16x8 h1 = gload16_coh(hrow + (1*16+sc16)*8);
      s16x8 h2 = gload16_coh(hrow + (2*16+sc16)*8);
      s16x8 h3 = gload16_coh(hrow + (3*16+sc16)*8);
      s16x8 h4 = gload16_coh(hrow + (4*16+sc16)*8);
      s16x8 h5 = gload16_coh(hrow + (5*16+sc16)*8);
      s16x8 h6 = gload16_coh(hrow + (6*16+sc16)*8);
      s16x8 h7 = gload16_coh(hrow + (7*16+sc16)*8);
      asm volatile("s_waitcnt vmcnt(0)" ::: "memory");
      *(s16x8*)(pSh + 0*4096) = h0;  *(s16x8*)(pSh + 1*4096) = h1;
      *(s16x8*)(pSh + 2*4096) = h2;  *(s16x8*)(pSh + 3*4096) = h3;
      *(s16x8*)(pSh + 4*4096) = h4;  *(s16x8*)(pSh + 5*4096) = h5;
      *(s16x8*)(pSh + 6*4096) = h6;  *(s16x8*)(pSh + 7*4096) = h7;
    }
    __syncthreads();

    // ---- h-MFMA: extend acc with h@Wh (this wave's K-half) ----
    #pragma unroll
    for(int kk=0;kk<16;kk++){
      const u16* p = (kk&1) ? pAo : pAe;
      s16x8 a0 = *(const s16x8*)(p + kk*1024);
      s16x8 a1 = *(const s16x8*)(p + kk*1024 + 128);
      acc00 = MF(a0, breg[0][kk], acc00);
      acc01 = MF(a0, breg[1][kk], acc01);
      acc10 = MF(a1, breg[0][kk], acc10);
      acc11 = MF(a1, breg[1][kk], acc11);
    }
    __syncthreads();   // all h-MFMA As reads retired -> zpart alias safe

    // ---- K-half partial exchange: zpart[gate*2+kg][row][33] (aliases As) ----
    #pragma unroll
    for(int j=0;j<4;j++){
      pzw[      j*33     ] = acc00[j];
      pzw[      j*33 + 16] = acc01[j];
      pzw[528 + j*33     ] = acc10[j];
      pzw[528 + j*33 + 16] = acc11[j];
    }
    __syncthreads();

    // ---- epilogue: z sums (bias pre-folded), gates, state update ----
    float nhv[2];
    #pragma unroll
    for(int e=0;e<2;e++){
      u8 cd = e ? cd1 : cd0;
      float zi  = pzr[   0 + e*528] + pzr[1056 + e*528];
      float zf_ = pzr[2112 + e*528] + pzr[3168 + e*528];
      float zg  = pzr[4224 + e*528] + pzr[5280 + e*528];
      float zo  = pzr[6336 + e*528] + pzr[7392 + e*528];
      bool d_ = cd & 1, m_ = cd & 2, m2 = cd & 4;
      float co = m_ ? c1r[e] : c2r[e];
      float nc = sigf(zf_)*co + sigf(zi)*tanh2(zg);
      float nhx = sigf(zo)*tanh2(nc);
      nhv[e] = nhx;
      float n1c = m_?nc:c1r[e], n2c = m_?c2r[e]:nc;
      float n1h = m_?nhx:h1r[e], n2h = m_?h2r[e]:nhx;
      if(d_){ n1c=0.f; n2c=0.f; n1h=0.f; n2h=0.f; }
      c1r[e]=n1c; c2r[e]=n2c; h1r[e]=n1h; h2r[e]=n2h;
      int grow = r0 + e*16 + erow;
      if(t<127)
        st_u16_coh(&houtp[(size_t)grow*1024 + j0 + ecol], f2b(m2 ? n1h : n2h));
      out[(size_t)(t*256 + grow)*1024 + j0 + ecol] = nhv[e];   // plain cached
    }
    asm volatile("s_waitcnt vmcnt(0)" ::: "memory");   // h at coherence point
    __syncthreads();                                   // epilogue zpart reads done
    if(t<127 && tid==0)
      __hip_atomic_fetch_add(flag, 1, __ATOMIC_RELAXED, __HIP_MEMORY_SCOPE_AGENT);

    // ---- free zone: x-part for step t+1 (reuses As; barrier-separated) ----
    if(t<127)
      xphase(xb + (size_t)((t+1)*256 + r0 + srow)*1024);
  }
}

// ---------------- host ----------------
extern "C" void kernel_launch(void* const* d_in, const int* in_sizes, int n_in,
                              void* d_out, int out_size, void* d_ws, size_t ws_size,
                              hipStream_t stream){
  const float* x   = (const float*)d_in[0];
  const float* c1i = (const float*)d_in[1];
  const float* h1i = (const float*)d_in[2];
  const float* c2i = (const float*)d_in[3];
  const float* h2i = (const float*)d_in[4];
  const float* Wi  = (const float*)d_in[5];
  const float* Wh  = (const float*)d_in[6];
  const float* bias= (const float*)d_in[7];
  const void* done_raw = d_in[8];
  const void* main_raw = d_in[9];
  float* out = (float*)d_out;

  char* ws = (char*)d_ws;
  size_t off=0;
  auto alloc=[&](size_t sz)->char*{ char* p = ws+off; off += (sz+255)&~(size_t)255; return p; };

  u16* xb   = (u16*)alloc(33554432ull*2);        // x as bf16 [32768][1024]
  u16* WiT  = (u16*)alloc(4096ull*1024*2);       // Wi^T bf16 [4096][1024]
  u16* WhT  = (u16*)alloc(4096ull*1024*2);       // Wh^T bf16 [4096][1024]
  u16* hs0  = (u16*)alloc(262144ull*2);
  u16* hs1  = (u16*)alloc(262144ull*2);
  u8* mcode = (u8*)alloc(32768);
  int* flag = (int*)alloc(256);
  int* ready= (int*)alloc(1024);
  (void)ws_size;

  detect_mask_mode<<<1,256,0,stream>>>((const u8*)done_raw, 32768, flag);
  build_mcode<<<64,256,0,stream>>>(done_raw, main_raw, mcode, 32768, flag);
  cvt_f32_bf16<<<32768,256,0,stream>>>(x, xb, 8388608);
  transpose_to_bf16<<<dim3(64,16),256,0,stream>>>(Wi, WiT, 1024, 4096);
  transpose_to_bf16<<<dim3(64,16),256,0,stream>>>(Wh, WhT, 1024, 4096);
  init_hsel<<<1024,256,0,stream>>>(h1i, h2i, mcode, hs0);
  zero_flags<<<1,256,0,stream>>>(ready, 256);

  lstm_fused<<<256,512,0,stream>>>(xb, WiT, WhT, bias, hs0, hs1,
                                   c1i, h1i, c2i, h2i, mcode, out, ready);
}